// Round 5
// baseline (755.292 us; speedup 1.0000x reference)
//
#include <hip/hip_runtime.h>
#include <hip/hip_bf16.h>
#include <stdint.h>
#include <math.h>

// Problem constants (B=1)
#define cH    2048
#define cQ    1024
#define cNH   32
#define cNKV  8
#define cKB   2048

#define INV_BIG   (1.0f/4194304.0f)   // 1/(2048*2048)
#define INV_SMALL (1.0f/1048576.0f)   // 1/(512*2048)

// ---------------------------------------------------------------------------
// Workspace layout (bytes). Total = 46,145,792.
#define WS_SUMS 0           // 8 doubles (5 used)
#define WS_DQ1  256         // 1024 f32
#define WS_DQ2  4352        // 1024 f32
#define WS_XQ   8448        // 1024x2048 bf16 (xq1; reused as xq2 after attention)
#define WS_WALL 4202752     // 5120x2048 bf16 weights; DEAD after fused GEMM ->
                            //   vtKB packed u32 [32*64][2048] at +0 (16MB),
                            //   vtP  packed u32 [8*64][1024]  at +16777216 (2MB)
#define WS_QB   25174272    // 1024x2048 f32 rotated q; reused as wqo after attn
#define WS_KB   33562880    // 1024x512 f32 rotated k; rope writes packed in place
#define WS_VB   35660032    // 1024x512 f32 v (source for vtrans)
#define WS_QN   37757184    // 1024x2048 f32 kb_q; reused as CTX (same rows+cols per block)
// memset-zero region for split-K atomics: [WS_QB, WS_QN+8MB) = 20,971,520 B

using short8  = __attribute__((ext_vector_type(8))) short;
using floatx4 = __attribute__((ext_vector_type(4))) float;

__device__ __forceinline__ void bsplit(float x, unsigned short& hi, unsigned short& lo) {
  __hip_bfloat16 h = __float2bfloat16(x);          // RN
  float hf = __bfloat162float(h);
  __hip_bfloat16 l = __float2bfloat16(x - hf);     // exact residual, RN again
  hi = *(unsigned short*)&h;
  lo = *(unsigned short*)&l;
}

// ---------------------------------------------------------------------------
__global__ void k_abssum5(const float* __restrict__ w0, const float* __restrict__ w1,
                          const float* __restrict__ w2, const float* __restrict__ w3,
                          const float* __restrict__ w4, double* __restrict__ out) {
  __shared__ double red[256];
  const int seg = blockIdx.y;
  const float* w = seg == 0 ? w0 : seg == 1 ? w1 : seg == 2 ? w2 : seg == 3 ? w3 : w4;
  const int n = (seg == 1 || seg == 2) ? 512 * 2048 : 2048 * 2048;
  double s = 0.0;
  for (int i = blockIdx.x * 256 + threadIdx.x; i < n; i += gridDim.x * 256)
    s += (double)fabsf(w[i]);
  red[threadIdx.x] = s;
  __syncthreads();
  for (int o = 128; o > 0; o >>= 1) {
    if ((int)threadIdx.x < o) red[threadIdx.x] += red[threadIdx.x + o];
    __syncthreads();
  }
  if (threadIdx.x == 0) atomicAdd(out + seg, red[0]);
}

__global__ void k_wquant4(const float* __restrict__ Wq, const float* __restrict__ Wk,
                          const float* __restrict__ Wv, const float* __restrict__ Wqn,
                          unsigned short* __restrict__ wall, const double* __restrict__ sums) {
  size_t i = (size_t)blockIdx.x * 256 + threadIdx.x;
  const float* src; size_t off; double s; float inv;
  if (i < 4194304)      { src = Wq;  off = 0;       s = sums[0]; inv = INV_BIG; }
  else if (i < 5242880) { src = Wk;  off = 4194304; s = sums[1]; inv = INV_SMALL; }
  else if (i < 6291456) { src = Wv;  off = 5242880; s = sums[2]; inv = INV_SMALL; }
  else                  { src = Wqn; off = 6291456; s = sums[4]; inv = INV_BIG; }
  float mean = (float)s * inv;
  float ws = 1.0f / fmaxf(mean, 1e-5f);
  float q = rintf(src[i - off] * ws);
  q = fminf(fmaxf(q, -1.0f), 1.0f);
  wall[i] = (unsigned short)(__float_as_uint(q) >> 16);
}

__global__ void k_wquant(const float* __restrict__ w, unsigned short* __restrict__ wq, int n,
                         const double* __restrict__ sum, float inv_n) {
  int i = blockIdx.x * 256 + threadIdx.x;
  if (i >= n) return;
  float mean = (float)(*sum) * inv_n;
  float ws = 1.0f / fmaxf(mean, 1e-5f);
  float q = rintf(w[i] * ws);
  q = fminf(fmaxf(q, -1.0f), 1.0f);
  wq[i] = (unsigned short)(__float_as_uint(q) >> 16);
}

__global__ void k_aquant(const float* __restrict__ x, unsigned short* __restrict__ xq,
                         float* __restrict__ dq, int K) {
  int t = blockIdx.x;
  const float* xr = x + (size_t)t * K;
  __shared__ float red[256];
  float m = 0.0f;
  for (int i = threadIdx.x; i < K; i += 256) m = fmaxf(m, fabsf(xr[i]));
  red[threadIdx.x] = m;
  __syncthreads();
  for (int o = 128; o > 0; o >>= 1) {
    if ((int)threadIdx.x < o) red[threadIdx.x] = fmaxf(red[threadIdx.x], red[threadIdx.x + o]);
    __syncthreads();
  }
  float amax = fmaxf(red[0], 1e-5f);
  float as = 127.0f / amax;
  for (int i = threadIdx.x; i < K; i += 256) {
    float q = rintf(xr[i] * as);
    q = fminf(fmaxf(q, -128.0f), 127.0f);
    xq[(size_t)t * K + i] = (unsigned short)(__float_as_uint(q) >> 16);
  }
  if (threadIdx.x == 0) dq[t] = amax / 127.0f;
}

// ---------------------------------------------------------------------------
// bf16-MFMA BitLinear GEMM, split-K over gridDim.z with f32 atomicAdd epilogue.
// Partial K-sums are exact integers -> atomic combine costs <=1 ulp.
// Outputs must be zeroed before launch.
__global__ __launch_bounds__(256) void k_gemm_mfma(
    const unsigned short* __restrict__ Aq, const unsigned short* __restrict__ Ball,
    const float* __restrict__ adq, const double* __restrict__ sums,
    float* __restrict__ oQ, float* __restrict__ oK,
    float* __restrict__ oV, float* __restrict__ oQN, int mode) {
  __shared__ unsigned short As[128 * 72];
  __shared__ unsigned short Bs[128 * 72];
  const int t = threadIdx.x;
  const int lane = t & 63;
  const int row16 = lane & 15, q = lane >> 4;
  const int w = t >> 6;
  const int wm = (w >> 1) * 64, wn = (w & 1) * 64;
  const int bx = blockIdx.x;
  const int m0 = blockIdx.y * 128;
  const int Kc = 2048 / gridDim.z;
  const int kbeg = blockIdx.z * Kc, kend = kbeg + Kc;
  const unsigned short* Bp = Ball + (size_t)bx * 128 * 2048;

  floatx4 acc[4][4];
#pragma unroll
  for (int g = 0; g < 4; ++g)
#pragma unroll
    for (int h = 0; h < 4; ++h) acc[g][h] = (floatx4){0.f, 0.f, 0.f, 0.f};

  for (int k0 = kbeg; k0 < kend; k0 += 64) {
#pragma unroll
    for (int i = 0; i < 4; ++i) {
      int c = t + 256 * i;
      int row = c >> 3, g8 = c & 7;
      *(uint4*)&As[row * 72 + g8 * 8] =
          *(const uint4*)(Aq + (size_t)(m0 + row) * 2048 + k0 + g8 * 8);
      *(uint4*)&Bs[row * 72 + g8 * 8] =
          *(const uint4*)(Bp + (size_t)row * 2048 + k0 + g8 * 8);
    }
    __syncthreads();
#pragma unroll
    for (int kk = 0; kk < 2; ++kk) {
      short8 af[4], bf[4];
#pragma unroll
      for (int g = 0; g < 4; ++g)
        af[g] = *(const short8*)&As[(wm + g * 16 + row16) * 72 + kk * 32 + q * 8];
#pragma unroll
      for (int h = 0; h < 4; ++h)
        bf[h] = *(const short8*)&Bs[(wn + h * 16 + row16) * 72 + kk * 32 + q * 8];
#pragma unroll
      for (int g = 0; g < 4; ++g)
#pragma unroll
        for (int h = 0; h < 4; ++h)
          acc[g][h] = __builtin_amdgcn_mfma_f32_16x16x32_bf16(af[g], bf[h], acc[g][h], 0, 0, 0);
    }
    __syncthreads();
  }

  float* outp; int Nout, nb0; float wdq;
  if (mode == 1)      { outp = oQ;  Nout = 2048; nb0 = bx * 128;        wdq = fmaxf((float)sums[3] * INV_BIG,   1e-5f); }
  else if (bx < 16)   { outp = oQ;  Nout = 2048; nb0 = bx * 128;        wdq = fmaxf((float)sums[0] * INV_BIG,   1e-5f); }
  else if (bx < 20)   { outp = oK;  Nout = 512;  nb0 = (bx - 16) * 128; wdq = fmaxf((float)sums[1] * INV_SMALL, 1e-5f); }
  else if (bx < 24)   { outp = oV;  Nout = 512;  nb0 = (bx - 20) * 128; wdq = fmaxf((float)sums[2] * INV_SMALL, 1e-5f); }
  else                { outp = oQN; Nout = 2048; nb0 = (bx - 24) * 128; wdq = fmaxf((float)sums[4] * INV_BIG,   1e-5f); }

#pragma unroll
  for (int g = 0; g < 4; ++g) {
#pragma unroll
    for (int r = 0; r < 4; ++r) {
      int m = m0 + wm + g * 16 + q * 4 + r;
      float s = adq[m] * wdq;
#pragma unroll
      for (int h = 0; h < 4; ++h) {
        int n = nb0 + wn + h * 16 + row16;
        atomicAdd(&outp[(size_t)m * Nout + n], acc[g][h][r] * s);
      }
    }
  }
}

// ---------------------------------------------------------------------------
// RoPE on Q (fp32 in place).
__global__ void k_rope(float* __restrict__ buf, const int* __restrict__ pos) {
  int t = blockIdx.x;
  int idx = threadIdx.x;         // h*32 + d, 1024 threads
  int h = idx >> 5, d = idx & 31;
  double p = (double)pos[t];
  double ang = p * pow(10000.0, -(double)d / 32.0);
  float c = (float)cos(ang), s = (float)sin(ang);
  float* q = buf + (size_t)t * 2048 + h * 64 + d;
  float v0 = q[0], v1 = q[32];
  q[0]  = v0 * c - v1 * s;
  q[32] = v1 * c + v0 * s;
}

// RoPE on K + packed hi/lo split, in place (thread owns elements d and d+32).
__global__ void k_ropek(float* __restrict__ buf, const int* __restrict__ pos) {
  int t = blockIdx.x;
  int idx = threadIdx.x;         // h*32 + d, 256 threads
  int h = idx >> 5, d = idx & 31;
  double p = (double)pos[t];
  double ang = p * pow(10000.0, -(double)d / 32.0);
  float c = (float)cos(ang), s = (float)sin(ang);
  float* q = buf + (size_t)t * 512 + h * 64 + d;
  float v0 = q[0], v1 = q[32];
  float r0 = v0 * c - v1 * s;
  float r1 = v1 * c + v0 * s;
  unsigned short hi, lo;
  bsplit(r0, hi, lo);
  ((unsigned int*)q)[0]  = (unsigned int)hi | ((unsigned int)lo << 16);
  bsplit(r1, hi, lo);
  ((unsigned int*)q)[32] = (unsigned int)hi | ((unsigned int)lo << 16);
}

// In-place packed hi/lo split of kbk (input is restored before every launch).
__global__ void k_packsplit(float* __restrict__ a, int n) {
  int i = blockIdx.x * 256 + threadIdx.x;
  if (i >= n) return;
  unsigned short hi, lo;
  bsplit(a[i], hi, lo);
  ((unsigned int*)a)[i] = (unsigned int)hi | ((unsigned int)lo << 16);
}

// Transpose+split V into packed V^T: vtKB [h*64+d][2048], vtP [hkv*64+d][1024].
__global__ __launch_bounds__(256) void k_vtrans(
    const float* __restrict__ kbv, const float* __restrict__ Vb,
    unsigned int* __restrict__ vtKB, unsigned int* __restrict__ vtP) {
  __shared__ float Lf[64 * 65];
  const int b = blockIdx.x;
  const float* src; unsigned int* dst; int srcStride, dstStride;
  if (b < 1024) {
    int h = b >> 5, kt = b & 31;
    src = kbv + ((size_t)h * cKB + kt * 64) * 64;
    srcStride = 64;
    dst = vtKB + (size_t)(h * 64) * 2048 + kt * 64;
    dstStride = 2048;
  } else {
    int bb = b - 1024;
    int hkv = bb >> 4, kt = bb & 15;
    src = Vb + (size_t)(kt * 64) * 512 + hkv * 64;
    srcStride = 512;
    dst = vtP + (size_t)(hkv * 64) * 1024 + kt * 64;
    dstStride = 1024;
  }
  const int t = threadIdx.x;
#pragma unroll
  for (int i = 0; i < 4; ++i) {
    int c = t + 256 * i;
    int row = c >> 4, c4 = (c & 15) * 4;
    float4 x = *(const float4*)(src + (size_t)row * srcStride + c4);
    Lf[row * 65 + c4 + 0] = x.x;
    Lf[row * 65 + c4 + 1] = x.y;
    Lf[row * 65 + c4 + 2] = x.z;
    Lf[row * 65 + c4 + 3] = x.w;
  }
  __syncthreads();
  const int lane = t & 63, w = t >> 6;
#pragma unroll
  for (int it = 0; it < 16; ++it) {
    int d = w + 4 * it;
    float x = Lf[lane * 65 + d];
    unsigned short hi, lo;
    bsplit(x, hi, lo);
    dst[(size_t)d * dstStride + lane] = (unsigned int)hi | ((unsigned int)lo << 16);
  }
}

// ---------------------------------------------------------------------------
// Split-bf16 MFMA flash attention, q-tile 128 (wave owns 32 q-rows in 2
// MFMA row-groups). K/V frags are read once per (kk,nt) and reused across
// both groups -> LDS frag traffic per q halved. P round-trips a per-wave
// 16-row buffer twice (same-wave DS ops are in-order; buffer aliases across
// groups so the compiler must preserve order). LDS = 54,272 B -> 3 blocks/CU.
__global__ __launch_bounds__(256, 3) void k_attn_mfma(
    const float* __restrict__ Qr, float* qnctx,
    const unsigned int* __restrict__ Kp,    // prompt K packed [1024][512]
    const unsigned int* __restrict__ kbkP,  // KB K packed [h][2048][64]
    const unsigned int* __restrict__ vtKB,  // KB V^T packed [h*64+d][2048]
    const unsigned int* __restrict__ vtP) { // prompt V^T packed [hkv*64+d][1024]
  __shared__ unsigned short Khi[64 * 72], Klo[64 * 72];
  __shared__ unsigned short Vhi[64 * 72], Vlo[64 * 72];   // [d][key]
  __shared__ unsigned int   Pbuf[4][16 * 68];             // per-wave, reused per group

  const int t = threadIdx.x;
  const int lane = t & 63;
  const int col = lane & 15;
  const int quad = lane >> 4;
  const int w = t >> 6;
  const int h = blockIdx.x;
  const int q0 = blockIdx.y * 128;
  const int hkv = h >> 2;
  const float kbbias = 0.69314718055994531f;   // log(4096)-log(2048)
  unsigned int* Pw = &Pbuf[w][0];

  short8 qh[2][2], ql[2][2];   // [group][kk]
  auto load_q = [&](const float* base) {
#pragma unroll
    for (int g = 0; g < 2; ++g)
#pragma unroll
      for (int kk = 0; kk < 2; ++kk) {
        const float* p = base + (size_t)(q0 + w * 32 + g * 16 + col) * 2048 +
                         h * 64 + kk * 32 + quad * 8;
        float4 a = *(const float4*)p;
        float4 b = *(const float4*)(p + 4);
        float xs[8] = {a.x, a.y, a.z, a.w, b.x, b.y, b.z, b.w};
#pragma unroll
        for (int j = 0; j < 8; ++j) {
          unsigned short hi, lo;
          bsplit(xs[j] * 0.125f, hi, lo);   // fold 1/sqrt(64), exact
          qh[g][kk][j] = (short)hi;
          ql[g][kk][j] = (short)lo;
        }
      }
  };
  load_q(qnctx);   // kb_q first (not rotated)

  floatx4 acco[2][4];
  float m_[2][4], l_[2][4];
#pragma unroll
  for (int g = 0; g < 2; ++g)
#pragma unroll
    for (int nt = 0; nt < 4; ++nt) acco[g][nt] = (floatx4){0.f, 0.f, 0.f, 0.f};
#pragma unroll
  for (int g = 0; g < 2; ++g)
#pragma unroll
    for (int r = 0; r < 4; ++r) { m_[g][r] = -3.0e38f; l_[g][r] = 0.f; }

  const int ntiles = 34 + (q0 >> 6);   // 32 KB + (2qb+2) causal prompt tiles
  for (int kt = 0; kt < ntiles; ++kt) {
    const bool isKB = kt < 32;
    const int k0 = isKB ? kt * 64 : (kt - 32) * 64;
    if (kt == 32) load_q(Qr);   // switch to rotated prompt q

    // ---- stage K [key][d] and V^T [d][key] from packed sources ----
    {
      const unsigned int* ksrc = isKB ? kbkP + ((size_t)h * cKB + k0) * 64
                                      : Kp + (size_t)k0 * 512 + hkv * 64;
      const int kstride = isKB ? 64 : 512;
      const unsigned int* vsrc = isKB ? vtKB + (size_t)(h * 64) * 2048 + k0
                                      : vtP + (size_t)(hkv * 64) * 1024 + k0;
      const int vstride = isKB ? 2048 : 1024;
#pragma unroll
      for (int i = 0; i < 4; ++i) {
        int c = t + 256 * i;
        int row = c >> 4, c4 = (c & 15) * 4;
        uint4 v = *(const uint4*)(ksrc + (size_t)row * kstride + c4);
        *(uint2*)&Khi[row * 72 + c4] =
            make_uint2((v.x & 0xffffu) | (v.y << 16), (v.z & 0xffffu) | (v.w << 16));
        *(uint2*)&Klo[row * 72 + c4] =
            make_uint2((v.x >> 16) | (v.y & 0xffff0000u), (v.z >> 16) | (v.w & 0xffff0000u));
        uint4 u = *(const uint4*)(vsrc + (size_t)row * vstride + c4);
        *(uint2*)&Vhi[row * 72 + c4] =
            make_uint2((u.x & 0xffffu) | (u.y << 16), (u.z & 0xffffu) | (u.w << 16));
        *(uint2*)&Vlo[row * 72 + c4] =
            make_uint2((u.x >> 16) | (u.y & 0xffff0000u), (u.z >> 16) | (u.w & 0xffff0000u));
      }
    }
    __syncthreads();

    // ---- S = Q.K^T: K frags read once, used for both q-groups ----
    floatx4 accs[2][4];
#pragma unroll
    for (int g = 0; g < 2; ++g)
#pragma unroll
      for (int nt = 0; nt < 4; ++nt) accs[g][nt] = (floatx4){0.f, 0.f, 0.f, 0.f};
#pragma unroll
    for (int kk = 0; kk < 2; ++kk)
#pragma unroll
      for (int nt = 0; nt < 4; ++nt) {
        const int ko = (nt * 16 + col) * 72 + kk * 32 + quad * 8;
        short8 khh = *(const short8*)&Khi[ko];
        short8 kll = *(const short8*)&Klo[ko];
#pragma unroll
        for (int g = 0; g < 2; ++g) {
          accs[g][nt] = __builtin_amdgcn_mfma_f32_16x16x32_bf16(qh[g][kk], khh, accs[g][nt], 0, 0, 0);
          accs[g][nt] = __builtin_amdgcn_mfma_f32_16x16x32_bf16(ql[g][kk], khh, accs[g][nt], 0, 0, 0);
          accs[g][nt] = __builtin_amdgcn_mfma_f32_16x16x32_bf16(qh[g][kk], kll, accs[g][nt], 0, 0, 0);
        }
      }

    // ---- bias/mask + online softmax per group (p replaces s in accs) ----
#pragma unroll
    for (int g = 0; g < 2; ++g) {
#pragma unroll
      for (int nt = 0; nt < 4; ++nt) {
        int kg = k0 + nt * 16 + col;
#pragma unroll
        for (int r = 0; r < 4; ++r) {
          int qg = q0 + w * 32 + g * 16 + quad * 4 + r;
          float b = isKB ? kbbias : ((kg <= qg) ? 0.0f : -1e9f);
          accs[g][nt][r] += b;
        }
      }
#pragma unroll
      for (int r = 0; r < 4; ++r) {
        float rmax = fmaxf(fmaxf(accs[g][0][r], accs[g][1][r]),
                           fmaxf(accs[g][2][r], accs[g][3][r]));
#pragma unroll
        for (int off = 8; off; off >>= 1) rmax = fmaxf(rmax, __shfl_xor(rmax, off));
        float mnew = fmaxf(m_[g][r], rmax);
        float alpha = __expf(m_[g][r] - mnew);
        float psum = 0.f;
#pragma unroll
        for (int nt = 0; nt < 4; ++nt) {
          float p = __expf(accs[g][nt][r] - mnew);
          accs[g][nt][r] = p;
          psum += p;
        }
#pragma unroll
        for (int off = 8; off; off >>= 1) psum += __shfl_xor(psum, off);
        l_[g][r] = l_[g][r] * alpha + psum;
        m_[g][r] = mnew;
#pragma unroll
        for (int nt = 0; nt < 4; ++nt) acco[g][nt][r] *= alpha;
      }
    }

    // ---- P via per-wave LDS buffer, one group at a time (in-order DS) ----
    short8 pfh[2][2], pfl[2][2];
#pragma unroll
    for (int g = 0; g < 2; ++g) {
#pragma unroll
      for (int nt = 0; nt < 4; ++nt)
#pragma unroll
        for (int r = 0; r < 4; ++r) {
          unsigned short ph, pl;
          bsplit(accs[g][nt][r], ph, pl);
          Pw[(quad * 4 + r) * 68 + nt * 16 + col] = (unsigned int)ph | ((unsigned int)pl << 16);
        }
#pragma unroll
      for (int kk = 0; kk < 2; ++kk) {
        uint4 pa = *(const uint4*)&Pw[col * 68 + kk * 32 + quad * 8];
        uint4 pb = *(const uint4*)&Pw[col * 68 + kk * 32 + quad * 8 + 4];
        union { unsigned int u[4]; short8 s; } uh, ul;
        uh.u[0] = (pa.x & 0xffffu) | (pa.y << 16);
        uh.u[1] = (pa.z & 0xffffu) | (pa.w << 16);
        uh.u[2] = (pb.x & 0xffffu) | (pb.y << 16);
        uh.u[3] = (pb.z & 0xffffu) | (pb.w << 16);
        ul.u[0] = (pa.x >> 16) | (pa.y & 0xffff0000u);
        ul.u[1] = (pa.z >> 16) | (pa.w & 0xffff0000u);
        ul.u[2] = (pb.x >> 16) | (pb.y & 0xffff0000u);
        ul.u[3] = (pb.z >> 16) | (pb.w & 0xffff0000u);
        pfh[g][kk] = uh.s;
        pfl[g][kk] = ul.s;
      }
    }

    // ---- O += P.V: V frags read once, used for both groups ----
#pragma unroll
    for (int kk = 0; kk < 2; ++kk)
#pragma unroll
      for (int nt = 0; nt < 4; ++nt) {
        const int vo = (nt * 16 + col) * 72 + kk * 32 + quad * 8;
        short8 vhh = *(const short8*)&Vhi[vo];
        short8 vll = *(const short8*)&Vlo[vo];
#pragma unroll
        for (int g = 0; g < 2; ++g) {
          acco[g][nt] = __builtin_amdgcn_mfma_f32_16x16x32_bf16(pfh[g][kk], vhh, acco[g][nt], 0, 0, 0);
          acco[g][nt] = __builtin_amdgcn_mfma_f32_16x16x32_bf16(pfl[g][kk], vhh, acco[g][nt], 0, 0, 0);
          acco[g][nt] = __builtin_amdgcn_mfma_f32_16x16x32_bf16(pfh[g][kk], vll, acco[g][nt], 0, 0, 0);
        }
      }
    __syncthreads();   // all K/V reads done before next staging overwrite
  }

#pragma unroll
  for (int g = 0; g < 2; ++g)
#pragma unroll
    for (int r = 0; r < 4; ++r) {
      float linv = 1.0f / l_[g][r];
#pragma unroll
      for (int nt = 0; nt < 4; ++nt)
        qnctx[(size_t)(q0 + w * 32 + g * 16 + quad * 4 + r) * 2048 +
              h * 64 + nt * 16 + col] = acco[g][nt][r] * linv;
    }
}

// ---------------------------------------------------------------------------
extern "C" void kernel_launch(void* const* d_in, const int* in_sizes, int n_in,
                              void* d_out, int out_size, void* d_ws, size_t ws_size,
                              hipStream_t stream) {
  (void)in_sizes; (void)n_in; (void)out_size; (void)ws_size;
  const float* hidden = (const float*)d_in[0];
  float* kbk = (float*)d_in[2];              // packed-split in place (restored each launch)
  const float* kbv = (const float*)d_in[3];
  const float* Wq  = (const float*)d_in[4];
  const float* Wk  = (const float*)d_in[5];
  const float* Wv  = (const float*)d_in[6];
  const float* Wo  = (const float*)d_in[7];
  const float* Wqn = (const float*)d_in[8];
  const int*   pos = (const int*)d_in[9];

  char* ws = (char*)d_ws;
  double* sums = (double*)(ws + WS_SUMS);
  float* dq1 = (float*)(ws + WS_DQ1);
  float* dq2 = (float*)(ws + WS_DQ2);
  unsigned short* xq   = (unsigned short*)(ws + WS_XQ);
  unsigned short* wall = (unsigned short*)(ws + WS_WALL);
  unsigned int* vtKB = (unsigned int*)(ws + WS_WALL);              // after GEMM
  unsigned int* vtP  = (unsigned int*)(ws + WS_WALL + 16777216);   // after GEMM
  unsigned short* wqo  = (unsigned short*)(ws + WS_QB);            // after attn
  float* Qb  = (float*)(ws + WS_QB);
  float* Kb  = (float*)(ws + WS_KB);
  float* Vb  = (float*)(ws + WS_VB);
  float* QNC = (float*)(ws + WS_QN);   // kb_q, then CTX

  hipMemsetAsync(sums, 0, 64, stream);
  // zero split-K atomic destinations: Qb/Kb/Vb/QNC (contiguous) and d_out
  hipMemsetAsync(ws + WS_QB, 0, 20971520, stream);
  hipMemsetAsync(d_out, 0, (size_t)cQ * cH * 4, stream);

  const int nBig = 2048 * 2048;

  k_abssum5<<<dim3(128, 5), 256, 0, stream>>>(Wq, Wk, Wv, Wo, Wqn, sums);
  k_wquant4<<<10485760 / 256, 256, 0, stream>>>(Wq, Wk, Wv, Wqn, wall, sums);
  k_aquant<<<cQ, 256, 0, stream>>>(hidden, xq, dq1, cH);

  // Fused Q/K/V/QN GEMM: N=5120, split-K=2 -> 640 blocks
  k_gemm_mfma<<<dim3(40, 8, 2), 256, 0, stream>>>(xq, wall, dq1, sums, Qb, Kb, Vb, QNC, 0);

  k_rope<<<cQ, 1024, 0, stream>>>(Qb, pos);
  k_ropek<<<cQ, 256, 0, stream>>>(Kb, pos);     // rope + pack K in place

  k_packsplit<<<16384, 256, 0, stream>>>(kbk, cNH * cKB * 64);
  k_vtrans<<<1024 + 128, 256, 0, stream>>>(kbv, Vb, vtKB, vtP);

  k_attn_mfma<<<dim3(cNH, cQ / 128), 256, 0, stream>>>(
      Qb, QNC, (const unsigned int*)Kb, (const unsigned int*)kbk, vtKB, vtP);

  k_wquant<<<nBig / 256, 256, 0, stream>>>(Wo, wqo, nBig, sums + 3, INV_BIG);
  k_aquant<<<cQ, 256, 0, stream>>>(QNC, xq, dq2, cH);

  // O projection: split-K=4 -> 512 blocks
  k_gemm_mfma<<<dim3(16, 8, 4), 256, 0, stream>>>(xq, wqo, dq2, sums,
                                                  (float*)d_out, nullptr, nullptr, nullptr, 1);
}

// Round 6
// 494.519 us; speedup vs baseline: 1.5273x; 1.5273x over previous
//
#include <hip/hip_runtime.h>
#include <hip/hip_bf16.h>
#include <stdint.h>
#include <math.h>

// Problem constants (B=1)
#define cH    2048
#define cQ    1024
#define cNH   32
#define cNKV  8
#define cKB   2048

#define INV_BIG   (1.0f/4194304.0f)   // 1/(2048*2048)
#define INV_SMALL (1.0f/1048576.0f)   // 1/(512*2048)

// ---------------------------------------------------------------------------
// Workspace layout (bytes). Total = 46,145,792.
#define WS_SUMS 0           // 8 doubles (5 used)
#define WS_DQ1  256         // 1024 f32
#define WS_DQ2  4352        // 1024 f32
#define WS_XQ   8448        // 1024x2048 bf16 (xq1; reused as xq2 after attention)
#define WS_WALL 4202752     // 5120x2048 bf16 weights; DEAD after fused GEMM ->
                            //   vtKB packed u32 [32*64][2048] at +0 (16MB),
                            //   vtP  packed u32 [8*64][1024]  at +16777216 (2MB)
#define WS_QB   25174272    // 1024x2048 f32 rotated q; reused as wqo after attn
#define WS_KB   33562880    // 1024x512 f32 rotated k; ropek writes packed in place
#define WS_VB   35660032    // 1024x512 f32 v (source for vtrans)
#define WS_QN   37757184    // 1024x2048 f32 kb_q; reused as CTX (same rows+cols per block)

using short8  = __attribute__((ext_vector_type(8))) short;
using floatx4 = __attribute__((ext_vector_type(4))) float;

__device__ __forceinline__ void bsplit(float x, unsigned short& hi, unsigned short& lo) {
  __hip_bfloat16 h = __float2bfloat16(x);          // RN
  float hf = __bfloat162float(h);
  __hip_bfloat16 l = __float2bfloat16(x - hf);     // exact residual, RN again
  hi = *(unsigned short*)&h;
  lo = *(unsigned short*)&l;
}

// ---------------------------------------------------------------------------
__global__ void k_abssum5(const float* __restrict__ w0, const float* __restrict__ w1,
                          const float* __restrict__ w2, const float* __restrict__ w3,
                          const float* __restrict__ w4, double* __restrict__ out) {
  __shared__ double red[256];
  const int seg = blockIdx.y;
  const float* w = seg == 0 ? w0 : seg == 1 ? w1 : seg == 2 ? w2 : seg == 3 ? w3 : w4;
  const int n = (seg == 1 || seg == 2) ? 512 * 2048 : 2048 * 2048;
  double s = 0.0;
  for (int i = blockIdx.x * 256 + threadIdx.x; i < n; i += gridDim.x * 256)
    s += (double)fabsf(w[i]);
  red[threadIdx.x] = s;
  __syncthreads();
  for (int o = 128; o > 0; o >>= 1) {
    if ((int)threadIdx.x < o) red[threadIdx.x] += red[threadIdx.x + o];
    __syncthreads();
  }
  if (threadIdx.x == 0) atomicAdd(out + seg, red[0]);
}

__global__ void k_wquant4(const float* __restrict__ Wq, const float* __restrict__ Wk,
                          const float* __restrict__ Wv, const float* __restrict__ Wqn,
                          unsigned short* __restrict__ wall, const double* __restrict__ sums) {
  size_t i = (size_t)blockIdx.x * 256 + threadIdx.x;
  const float* src; size_t off; double s; float inv;
  if (i < 4194304)      { src = Wq;  off = 0;       s = sums[0]; inv = INV_BIG; }
  else if (i < 5242880) { src = Wk;  off = 4194304; s = sums[1]; inv = INV_SMALL; }
  else if (i < 6291456) { src = Wv;  off = 5242880; s = sums[2]; inv = INV_SMALL; }
  else                  { src = Wqn; off = 6291456; s = sums[4]; inv = INV_BIG; }
  float mean = (float)s * inv;
  float ws = 1.0f / fmaxf(mean, 1e-5f);
  float q = rintf(src[i - off] * ws);
  q = fminf(fmaxf(q, -1.0f), 1.0f);
  wall[i] = (unsigned short)(__float_as_uint(q) >> 16);
}

__global__ void k_wquant(const float* __restrict__ w, unsigned short* __restrict__ wq, int n,
                         const double* __restrict__ sum, float inv_n) {
  int i = blockIdx.x * 256 + threadIdx.x;
  if (i >= n) return;
  float mean = (float)(*sum) * inv_n;
  float ws = 1.0f / fmaxf(mean, 1e-5f);
  float q = rintf(w[i] * ws);
  q = fminf(fmaxf(q, -1.0f), 1.0f);
  wq[i] = (unsigned short)(__float_as_uint(q) >> 16);
}

__global__ void k_aquant(const float* __restrict__ x, unsigned short* __restrict__ xq,
                         float* __restrict__ dq, int K) {
  int t = blockIdx.x;
  const float* xr = x + (size_t)t * K;
  __shared__ float red[256];
  float m = 0.0f;
  for (int i = threadIdx.x; i < K; i += 256) m = fmaxf(m, fabsf(xr[i]));
  red[threadIdx.x] = m;
  __syncthreads();
  for (int o = 128; o > 0; o >>= 1) {
    if ((int)threadIdx.x < o) red[threadIdx.x] = fmaxf(red[threadIdx.x], red[threadIdx.x + o]);
    __syncthreads();
  }
  float amax = fmaxf(red[0], 1e-5f);
  float as = 127.0f / amax;
  for (int i = threadIdx.x; i < K; i += 256) {
    float q = rintf(xr[i] * as);
    q = fminf(fmaxf(q, -128.0f), 127.0f);
    xq[(size_t)t * K + i] = (unsigned short)(__float_as_uint(q) >> 16);
  }
  if (threadIdx.x == 0) dq[t] = amax / 127.0f;
}

// ---------------------------------------------------------------------------
// Fused QKVN bf16-MFMA BitLinear GEMM, 64x128 block tile (M-tile halved vs
// 128x128 to double the grid: 40x16 = 640 blocks ~= 2.5/CU; R5 showed the
// 320-block version was occupancy-starved). 4 waves in 2(m)x2(n), each wave
// 32x64 via acc[2][4]. LDS 27,648 B. Exact integer arithmetic.
__global__ __launch_bounds__(256) void k_gemm_fused(
    const unsigned short* __restrict__ Aq, const unsigned short* __restrict__ Ball,
    const float* __restrict__ adq, const double* __restrict__ sums,
    float* __restrict__ oQ, float* __restrict__ oK,
    float* __restrict__ oV, float* __restrict__ oQN) {
  __shared__ unsigned short As[64 * 72];
  __shared__ unsigned short Bs[128 * 72];
  const int t = threadIdx.x;
  const int lane = t & 63;
  const int col16 = lane & 15, quad = lane >> 4;
  const int w = t >> 6;
  const int wm = (w >> 1) * 32, wn = (w & 1) * 64;
  const int bx = blockIdx.x;
  const int m0 = blockIdx.y * 64;
  const unsigned short* Bp = Ball + (size_t)bx * 128 * 2048;

  floatx4 acc[2][4];
#pragma unroll
  for (int g = 0; g < 2; ++g)
#pragma unroll
    for (int h = 0; h < 4; ++h) acc[g][h] = (floatx4){0.f, 0.f, 0.f, 0.f};

  for (int k0 = 0; k0 < 2048; k0 += 64) {
#pragma unroll
    for (int i = 0; i < 6; ++i) {          // 192 rows x 8 granules (A:64, B:128)
      int c = t + 256 * i;
      int row = c >> 3, g8 = c & 7;
      if (row < 64) {
        *(uint4*)&As[row * 72 + g8 * 8] =
            *(const uint4*)(Aq + (size_t)(m0 + row) * 2048 + k0 + g8 * 8);
      } else {
        *(uint4*)&Bs[(row - 64) * 72 + g8 * 8] =
            *(const uint4*)(Bp + (size_t)(row - 64) * 2048 + k0 + g8 * 8);
      }
    }
    __syncthreads();
#pragma unroll
    for (int kk = 0; kk < 2; ++kk) {
      short8 af[2], bf[4];
#pragma unroll
      for (int g = 0; g < 2; ++g)
        af[g] = *(const short8*)&As[(wm + g * 16 + col16) * 72 + kk * 32 + quad * 8];
#pragma unroll
      for (int h = 0; h < 4; ++h)
        bf[h] = *(const short8*)&Bs[(wn + h * 16 + col16) * 72 + kk * 32 + quad * 8];
#pragma unroll
      for (int g = 0; g < 2; ++g)
#pragma unroll
        for (int h = 0; h < 4; ++h)
          acc[g][h] = __builtin_amdgcn_mfma_f32_16x16x32_bf16(af[g], bf[h], acc[g][h], 0, 0, 0);
    }
    __syncthreads();
  }

  float* outp; int Nout, nb0; float wdq;
  if (bx < 16)      { outp = oQ;  Nout = 2048; nb0 = bx * 128;        wdq = fmaxf((float)sums[0] * INV_BIG,   1e-5f); }
  else if (bx < 20) { outp = oK;  Nout = 512;  nb0 = (bx - 16) * 128; wdq = fmaxf((float)sums[1] * INV_SMALL, 1e-5f); }
  else if (bx < 24) { outp = oV;  Nout = 512;  nb0 = (bx - 20) * 128; wdq = fmaxf((float)sums[2] * INV_SMALL, 1e-5f); }
  else              { outp = oQN; Nout = 2048; nb0 = (bx - 24) * 128; wdq = fmaxf((float)sums[4] * INV_BIG,   1e-5f); }

#pragma unroll
  for (int g = 0; g < 2; ++g)
#pragma unroll
    for (int r = 0; r < 4; ++r) {
      int m = m0 + wm + g * 16 + quad * 4 + r;
      float s = adq[m] * wdq;
#pragma unroll
      for (int h = 0; h < 4; ++h)
        outp[(size_t)m * Nout + nb0 + wn + h * 16 + col16] = acc[g][h][r] * s;
    }
}

// O-projection GEMM, 64x64 tile -> grid 32x16 = 512 blocks = 2/CU.
// 4 waves in 2x2, each 32x32 via acc[2][2]. LDS 18,432 B.
__global__ __launch_bounds__(256) void k_gemm_o(
    const unsigned short* __restrict__ Aq, const unsigned short* __restrict__ Bq,
    const float* __restrict__ adq, const double* __restrict__ sums,
    float* __restrict__ out) {
  __shared__ unsigned short As[64 * 72];
  __shared__ unsigned short Bs[64 * 72];
  const int t = threadIdx.x;
  const int lane = t & 63;
  const int col16 = lane & 15, quad = lane >> 4;
  const int w = t >> 6;
  const int wm = (w >> 1) * 32, wn = (w & 1) * 32;
  const int n0 = blockIdx.x * 64;
  const int m0 = blockIdx.y * 64;

  floatx4 acc[2][2];
#pragma unroll
  for (int g = 0; g < 2; ++g)
#pragma unroll
    for (int h = 0; h < 2; ++h) acc[g][h] = (floatx4){0.f, 0.f, 0.f, 0.f};

  for (int k0 = 0; k0 < 2048; k0 += 64) {
#pragma unroll
    for (int i = 0; i < 4; ++i) {          // 128 rows (A:64, B:64)
      int c = t + 256 * i;
      int row = c >> 3, g8 = c & 7;
      if (row < 64) {
        *(uint4*)&As[row * 72 + g8 * 8] =
            *(const uint4*)(Aq + (size_t)(m0 + row) * 2048 + k0 + g8 * 8);
      } else {
        *(uint4*)&Bs[(row - 64) * 72 + g8 * 8] =
            *(const uint4*)(Bq + (size_t)(n0 + row - 64) * 2048 + k0 + g8 * 8);
      }
    }
    __syncthreads();
#pragma unroll
    for (int kk = 0; kk < 2; ++kk) {
      short8 af[2], bf[2];
#pragma unroll
      for (int g = 0; g < 2; ++g)
        af[g] = *(const short8*)&As[(wm + g * 16 + col16) * 72 + kk * 32 + quad * 8];
#pragma unroll
      for (int h = 0; h < 2; ++h)
        bf[h] = *(const short8*)&Bs[(wn + h * 16 + col16) * 72 + kk * 32 + quad * 8];
#pragma unroll
      for (int g = 0; g < 2; ++g)
#pragma unroll
        for (int h = 0; h < 2; ++h)
          acc[g][h] = __builtin_amdgcn_mfma_f32_16x16x32_bf16(af[g], bf[h], acc[g][h], 0, 0, 0);
    }
    __syncthreads();
  }

  float wdq = fmaxf((float)sums[3] * INV_BIG, 1e-5f);
#pragma unroll
  for (int g = 0; g < 2; ++g)
#pragma unroll
    for (int r = 0; r < 4; ++r) {
      int m = m0 + wm + g * 16 + quad * 4 + r;
      float s = adq[m] * wdq;
#pragma unroll
      for (int h = 0; h < 2; ++h)
        out[(size_t)m * 2048 + n0 + wn + h * 16 + col16] = acc[g][h][r] * s;
    }
}

// ---------------------------------------------------------------------------
__global__ void k_rope(float* __restrict__ buf, const int* __restrict__ pos) {
  int t = blockIdx.x;
  int idx = threadIdx.x;         // h*32 + d, 1024 threads
  int h = idx >> 5, d = idx & 31;
  double p = (double)pos[t];
  double ang = p * pow(10000.0, -(double)d / 32.0);
  float c = (float)cos(ang), s = (float)sin(ang);
  float* q = buf + (size_t)t * 2048 + h * 64 + d;
  float v0 = q[0], v1 = q[32];
  q[0]  = v0 * c - v1 * s;
  q[32] = v1 * c + v0 * s;
}

// RoPE on K + packed hi/lo split, in place.
__global__ void k_ropek(float* __restrict__ buf, const int* __restrict__ pos) {
  int t = blockIdx.x;
  int idx = threadIdx.x;         // h*32 + d, 256 threads
  int h = idx >> 5, d = idx & 31;
  double p = (double)pos[t];
  double ang = p * pow(10000.0, -(double)d / 32.0);
  float c = (float)cos(ang), s = (float)sin(ang);
  float* q = buf + (size_t)t * 512 + h * 64 + d;
  float v0 = q[0], v1 = q[32];
  float r0 = v0 * c - v1 * s;
  float r1 = v1 * c + v0 * s;
  unsigned short hi, lo;
  bsplit(r0, hi, lo);
  ((unsigned int*)q)[0]  = (unsigned int)hi | ((unsigned int)lo << 16);
  bsplit(r1, hi, lo);
  ((unsigned int*)q)[32] = (unsigned int)hi | ((unsigned int)lo << 16);
}

// In-place packed hi/lo split of kbk (input restored before every launch).
__global__ void k_packsplit(float* __restrict__ a, int n) {
  int i = blockIdx.x * 256 + threadIdx.x;
  if (i >= n) return;
  unsigned short hi, lo;
  bsplit(a[i], hi, lo);
  ((unsigned int*)a)[i] = (unsigned int)hi | ((unsigned int)lo << 16);
}

// Transpose+split V into packed V^T: vtKB [h*64+d][2048], vtP [hkv*64+d][1024].
__global__ __launch_bounds__(256) void k_vtrans(
    const float* __restrict__ kbv, const float* __restrict__ Vb,
    unsigned int* __restrict__ vtKB, unsigned int* __restrict__ vtP) {
  __shared__ float Lf[64 * 65];
  const int b = blockIdx.x;
  const float* src; unsigned int* dst; int srcStride, dstStride;
  if (b < 1024) {
    int h = b >> 5, kt = b & 31;
    src = kbv + ((size_t)h * cKB + kt * 64) * 64;
    srcStride = 64;
    dst = vtKB + (size_t)(h * 64) * 2048 + kt * 64;
    dstStride = 2048;
  } else {
    int bb = b - 1024;
    int hkv = bb >> 4, kt = bb & 15;
    src = Vb + (size_t)(kt * 64) * 512 + hkv * 64;
    srcStride = 512;
    dst = vtP + (size_t)(hkv * 64) * 1024 + kt * 64;
    dstStride = 1024;
  }
  const int t = threadIdx.x;
#pragma unroll
  for (int i = 0; i < 4; ++i) {
    int c = t + 256 * i;
    int row = c >> 4, c4 = (c & 15) * 4;
    float4 x = *(const float4*)(src + (size_t)row * srcStride + c4);
    Lf[row * 65 + c4 + 0] = x.x;
    Lf[row * 65 + c4 + 1] = x.y;
    Lf[row * 65 + c4 + 2] = x.z;
    Lf[row * 65 + c4 + 3] = x.w;
  }
  __syncthreads();
  const int lane = t & 63, w = t >> 6;
#pragma unroll
  for (int it = 0; it < 16; ++it) {
    int d = w + 4 * it;
    float x = Lf[lane * 65 + d];
    unsigned short hi, lo;
    bsplit(x, hi, lo);
    dst[(size_t)d * dstStride + lane] = (unsigned int)hi | ((unsigned int)lo << 16);
  }
}

// ---------------------------------------------------------------------------
// Split-bf16 MFMA flash attention — R4 structure (q-tile 64, grid 32x16=512
// blocks = 2/CU; R5 proved q-tile 128's 256-block grid serializes the CU).
__global__ __launch_bounds__(256, 3) void k_attn_mfma(
    const float* __restrict__ Qr, float* qnctx,
    const unsigned int* __restrict__ Kp,    // prompt K packed [1024][512]
    const unsigned int* __restrict__ kbkP,  // KB K packed [h][2048][64]
    const unsigned int* __restrict__ vtKB,  // KB V^T packed [h*64+d][2048]
    const unsigned int* __restrict__ vtP) { // prompt V^T packed [hkv*64+d][1024]
  __shared__ unsigned short Khi[64 * 72], Klo[64 * 72];
  __shared__ unsigned short Vhi[64 * 72], Vlo[64 * 72];   // [d][key]
  __shared__ unsigned int   Pbuf[4][16 * 68];             // per-wave

  const int t = threadIdx.x;
  const int lane = t & 63;
  const int col = lane & 15;
  const int quad = lane >> 4;
  const int w = t >> 6;
  const int h = blockIdx.x;
  const int q0 = blockIdx.y * 64;
  const int hkv = h >> 2;
  const float kbbias = 0.69314718055994531f;   // log(4096)-log(2048)
  unsigned int* Pw = &Pbuf[w][0];

  short8 qh[2], ql[2];
  auto load_q = [&](const float* base) {
#pragma unroll
    for (int kk = 0; kk < 2; ++kk) {
      const float* p = base + (size_t)(q0 + w * 16 + col) * 2048 + h * 64 + kk * 32 + quad * 8;
      float4 a = *(const float4*)p;
      float4 b = *(const float4*)(p + 4);
      float xs[8] = {a.x, a.y, a.z, a.w, b.x, b.y, b.z, b.w};
#pragma unroll
      for (int j = 0; j < 8; ++j) {
        unsigned short hi, lo;
        bsplit(xs[j] * 0.125f, hi, lo);   // fold 1/sqrt(64), exact
        qh[kk][j] = (short)hi;
        ql[kk][j] = (short)lo;
      }
    }
  };
  load_q(qnctx);   // kb_q first (not rotated)

  floatx4 acco[4];
  float m_[4], l_[4];
#pragma unroll
  for (int nt = 0; nt < 4; ++nt) acco[nt] = (floatx4){0.f, 0.f, 0.f, 0.f};
#pragma unroll
  for (int r = 0; r < 4; ++r) { m_[r] = -3.0e38f; l_[r] = 0.f; }

  const int ntiles = 32 + (q0 >> 6) + 1;
  for (int kt = 0; kt < ntiles; ++kt) {
    const bool isKB = kt < 32;
    const int k0 = isKB ? kt * 64 : (kt - 32) * 64;
    if (kt == 32) load_q(Qr);   // switch to rotated prompt q

    {
      const unsigned int* ksrc = isKB ? kbkP + ((size_t)h * cKB + k0) * 64
                                      : Kp + (size_t)k0 * 512 + hkv * 64;
      const int kstride = isKB ? 64 : 512;
      const unsigned int* vsrc = isKB ? vtKB + (size_t)(h * 64) * 2048 + k0
                                      : vtP + (size_t)(hkv * 64) * 1024 + k0;
      const int vstride = isKB ? 2048 : 1024;
#pragma unroll
      for (int i = 0; i < 4; ++i) {
        int c = t + 256 * i;
        int row = c >> 4, c4 = (c & 15) * 4;
        uint4 v = *(const uint4*)(ksrc + (size_t)row * kstride + c4);
        *(uint2*)&Khi[row * 72 + c4] =
            make_uint2((v.x & 0xffffu) | (v.y << 16), (v.z & 0xffffu) | (v.w << 16));
        *(uint2*)&Klo[row * 72 + c4] =
            make_uint2((v.x >> 16) | (v.y & 0xffff0000u), (v.z >> 16) | (v.w & 0xffff0000u));
        uint4 u = *(const uint4*)(vsrc + (size_t)row * vstride + c4);
        *(uint2*)&Vhi[row * 72 + c4] =
            make_uint2((u.x & 0xffffu) | (u.y << 16), (u.z & 0xffffu) | (u.w << 16));
        *(uint2*)&Vlo[row * 72 + c4] =
            make_uint2((u.x >> 16) | (u.y & 0xffff0000u), (u.z >> 16) | (u.w & 0xffff0000u));
      }
    }
    __syncthreads();

    floatx4 accs[4];
#pragma unroll
    for (int nt = 0; nt < 4; ++nt) accs[nt] = (floatx4){0.f, 0.f, 0.f, 0.f};
#pragma unroll
    for (int kk = 0; kk < 2; ++kk) {
#pragma unroll
      for (int nt = 0; nt < 4; ++nt) {
        const int ko = (nt * 16 + col) * 72 + kk * 32 + quad * 8;
        short8 khh = *(const short8*)&Khi[ko];
        short8 kll = *(const short8*)&Klo[ko];
        accs[nt] = __builtin_amdgcn_mfma_f32_16x16x32_bf16(qh[kk], khh, accs[nt], 0, 0, 0);
        accs[nt] = __builtin_amdgcn_mfma_f32_16x16x32_bf16(ql[kk], khh, accs[nt], 0, 0, 0);
        accs[nt] = __builtin_amdgcn_mfma_f32_16x16x32_bf16(qh[kk], kll, accs[nt], 0, 0, 0);
      }
    }

    float sv[4][4];
#pragma unroll
    for (int nt = 0; nt < 4; ++nt) {
      int kg = k0 + nt * 16 + col;
#pragma unroll
      for (int r = 0; r < 4; ++r) {
        int qg = q0 + w * 16 + quad * 4 + r;
        float b = isKB ? kbbias : ((kg <= qg) ? 0.0f : -1e9f);
        sv[nt][r] = accs[nt][r] + b;
      }
    }
#pragma unroll
    for (int r = 0; r < 4; ++r) {
      float rmax = fmaxf(fmaxf(sv[0][r], sv[1][r]), fmaxf(sv[2][r], sv[3][r]));
#pragma unroll
      for (int off = 8; off; off >>= 1) rmax = fmaxf(rmax, __shfl_xor(rmax, off));
      float mnew = fmaxf(m_[r], rmax);
      float alpha = __expf(m_[r] - mnew);
      float psum = 0.f;
#pragma unroll
      for (int nt = 0; nt < 4; ++nt) {
        float p = __expf(sv[nt][r] - mnew);
        sv[nt][r] = p;
        psum += p;
      }
#pragma unroll
      for (int off = 8; off; off >>= 1) psum += __shfl_xor(psum, off);
      l_[r] = l_[r] * alpha + psum;
      m_[r] = mnew;
#pragma unroll
      for (int nt = 0; nt < 4; ++nt) acco[nt][r] *= alpha;
    }

#pragma unroll
    for (int nt = 0; nt < 4; ++nt)
#pragma unroll
      for (int r = 0; r < 4; ++r) {
        unsigned short ph, pl;
        bsplit(sv[nt][r], ph, pl);
        Pw[(quad * 4 + r) * 68 + nt * 16 + col] = (unsigned int)ph | ((unsigned int)pl << 16);
      }

#pragma unroll
    for (int kk = 0; kk < 2; ++kk) {
      uint4 pa = *(const uint4*)&Pw[col * 68 + kk * 32 + quad * 8];
      uint4 pb = *(const uint4*)&Pw[col * 68 + kk * 32 + quad * 8 + 4];
      union { unsigned int u[4]; short8 s; } uh, ul;
      uh.u[0] = (pa.x & 0xffffu) | (pa.y << 16);
      uh.u[1] = (pa.z & 0xffffu) | (pa.w << 16);
      uh.u[2] = (pb.x & 0xffffu) | (pb.y << 16);
      uh.u[3] = (pb.z & 0xffffu) | (pb.w << 16);
      ul.u[0] = (pa.x >> 16) | (pa.y & 0xffff0000u);
      ul.u[1] = (pa.z >> 16) | (pa.w & 0xffff0000u);
      ul.u[2] = (pb.x >> 16) | (pb.y & 0xffff0000u);
      ul.u[3] = (pb.z >> 16) | (pb.w & 0xffff0000u);
      short8 ph8 = uh.s, pl8 = ul.s;
#pragma unroll
      for (int nt = 0; nt < 4; ++nt) {
        const int vo = (nt * 16 + col) * 72 + kk * 32 + quad * 8;
        short8 vhh = *(const short8*)&Vhi[vo];
        short8 vll = *(const short8*)&Vlo[vo];
        acco[nt] = __builtin_amdgcn_mfma_f32_16x16x32_bf16(ph8, vhh, acco[nt], 0, 0, 0);
        acco[nt] = __builtin_amdgcn_mfma_f32_16x16x32_bf16(pl8, vhh, acco[nt], 0, 0, 0);
        acco[nt] = __builtin_amdgcn_mfma_f32_16x16x32_bf16(ph8, vll, acco[nt], 0, 0, 0);
      }
    }
    __syncthreads();   // all K/V reads done before next staging overwrite
  }

#pragma unroll
  for (int r = 0; r < 4; ++r) {
    float linv = 1.0f / l_[r];
#pragma unroll
    for (int nt = 0; nt < 4; ++nt)
      qnctx[(size_t)(q0 + w * 16 + quad * 4 + r) * 2048 + h * 64 + nt * 16 + col] =
          acco[nt][r] * linv;
  }
}

// ---------------------------------------------------------------------------
extern "C" void kernel_launch(void* const* d_in, const int* in_sizes, int n_in,
                              void* d_out, int out_size, void* d_ws, size_t ws_size,
                              hipStream_t stream) {
  (void)in_sizes; (void)n_in; (void)out_size; (void)ws_size;
  const float* hidden = (const float*)d_in[0];
  float* kbk = (float*)d_in[2];              // packed-split in place (restored each launch)
  const float* kbv = (const float*)d_in[3];
  const float* Wq  = (const float*)d_in[4];
  const float* Wk  = (const float*)d_in[5];
  const float* Wv  = (const float*)d_in[6];
  const float* Wo  = (const float*)d_in[7];
  const float* Wqn = (const float*)d_in[8];
  const int*   pos = (const int*)d_in[9];

  char* ws = (char*)d_ws;
  double* sums = (double*)(ws + WS_SUMS);
  float* dq1 = (float*)(ws + WS_DQ1);
  float* dq2 = (float*)(ws + WS_DQ2);
  unsigned short* xq   = (unsigned short*)(ws + WS_XQ);
  unsigned short* wall = (unsigned short*)(ws + WS_WALL);
  unsigned int* vtKB = (unsigned int*)(ws + WS_WALL);              // after GEMM
  unsigned int* vtP  = (unsigned int*)(ws + WS_WALL + 16777216);   // after GEMM
  unsigned short* wqo  = (unsigned short*)(ws + WS_QB);            // after attn
  float* Qb  = (float*)(ws + WS_QB);
  float* Kb  = (float*)(ws + WS_KB);
  float* Vb  = (float*)(ws + WS_VB);
  float* QNC = (float*)(ws + WS_QN);   // kb_q, then CTX

  hipMemsetAsync(sums, 0, 64, stream);

  const int nBig = 2048 * 2048;

  k_abssum5<<<dim3(128, 5), 256, 0, stream>>>(Wq, Wk, Wv, Wo, Wqn, sums);
  k_wquant4<<<10485760 / 256, 256, 0, stream>>>(Wq, Wk, Wv, Wqn, wall, sums);
  k_aquant<<<cQ, 256, 0, stream>>>(hidden, xq, dq1, cH);

  // Fused Q/K/V/QN GEMM: 64x128 tiles -> grid 40x16 = 640 blocks
  k_gemm_fused<<<dim3(40, 16), 256, 0, stream>>>(xq, wall, dq1, sums, Qb, Kb, Vb, QNC);

  k_rope<<<cQ, 1024, 0, stream>>>(Qb, pos);
  k_ropek<<<cQ, 256, 0, stream>>>(Kb, pos);     // rope + pack K in place

  k_packsplit<<<16384, 256, 0, stream>>>(kbk, cNH * cKB * 64);
  k_vtrans<<<1024 + 128, 256, 0, stream>>>(kbv, Vb, vtKB, vtP);

  k_attn_mfma<<<dim3(cNH, cQ / 64), 256, 0, stream>>>(
      Qb, QNC, (const unsigned int*)Kb, (const unsigned int*)kbk, vtKB, vtP);

  k_wquant<<<nBig / 256, 256, 0, stream>>>(Wo, wqo, nBig, sums + 3, INV_BIG);
  k_aquant<<<cQ, 256, 0, stream>>>(QNC, xq, dq2, cH);

  // O projection: 64x64 tiles -> grid 32x16 = 512 blocks
  k_gemm_o<<<dim3(32, 16), 256, 0, stream>>>(xq, wqo, dq2, sums, (float*)d_out);
}

// Round 7
// 415.706 us; speedup vs baseline: 1.8169x; 1.1896x over previous
//
#include <hip/hip_runtime.h>
#include <hip/hip_bf16.h>
#include <stdint.h>
#include <math.h>

// Problem constants (B=1)
#define cH    2048
#define cQ    1024
#define cNH   32
#define cNKV  8
#define cKB   2048

#define INV_BIG   (1.0f/4194304.0f)   // 1/(2048*2048)
#define INV_SMALL (1.0f/1048576.0f)   // 1/(512*2048)

// ---------------------------------------------------------------------------
// Workspace layout (bytes). Total = 46,407,936 (<= proven 48,242,944).
#define WS_SUMS 0           // 8 doubles (5 used)
#define WS_DQ1  256         // 1024 f32
#define WS_DQ2  4352        // 1024 f32
#define WS_XQ   8448        // 1024x2048 bf16 (xq1; reused as xq2 after attention)
#define WS_WALL 4202752     // 5120x2048 bf16 weights; DEAD after fused GEMM ->
                            //   vtKB packed u32 [32*64][2048] at +0 (16MB),
                            //   vtP  packed u32 [8*64][1024]  at +16777216 (2MB)
#define WS_QB   25174272    // 1024x2048 f32 rotated q; reused as wqo after attn
#define WS_KB   33562880    // 1024x512 u32 rotated+packed k (gemm epilogue writes packed)
#define WS_VB   35660032    // 1024x512 f32 v (source for vtrans)
#define WS_QN   37757184    // 1024x2048 f32 kb_q; reused as CTX (same rows+cols per block)
#define WS_ROPET 46145792   // 1024x32 float2 cos/sin table (262,144 B)

using short8  = __attribute__((ext_vector_type(8))) short;
using floatx4 = __attribute__((ext_vector_type(4))) float;

__device__ __forceinline__ void bsplit(float x, unsigned short& hi, unsigned short& lo) {
  __hip_bfloat16 h = __float2bfloat16(x);          // RN
  float hf = __bfloat162float(h);
  __hip_bfloat16 l = __float2bfloat16(x - hf);     // exact residual, RN again
  hi = *(unsigned short*)&h;
  lo = *(unsigned short*)&l;
}

__device__ __forceinline__ unsigned short tern(float v, float ws) {
  float q = rintf(v * ws);
  q = fminf(fmaxf(q, -1.0f), 1.0f);
  return (unsigned short)(__float_as_uint(q) >> 16);
}

// ---------------------------------------------------------------------------
// RoPE cos/sin table: 1024 positions x 32 freqs, fp64 math once.
__global__ void k_ropetab(const int* __restrict__ pos, float2* __restrict__ tab) {
  int i = blockIdx.x * 256 + threadIdx.x;   // 32768
  int t = i >> 5, d = i & 31;
  double p = (double)pos[t];
  double ang = p * pow(10000.0, -(double)d / 32.0);
  tab[i] = make_float2((float)cos(ang), (float)sin(ang));
}

// ---------------------------------------------------------------------------
__global__ void k_abssum5(const float* __restrict__ w0, const float* __restrict__ w1,
                          const float* __restrict__ w2, const float* __restrict__ w3,
                          const float* __restrict__ w4, double* __restrict__ out) {
  __shared__ double red[256];
  const int seg = blockIdx.y;
  const float* w = seg == 0 ? w0 : seg == 1 ? w1 : seg == 2 ? w2 : seg == 3 ? w3 : w4;
  const int n4 = ((seg == 1 || seg == 2) ? 512 * 2048 : 2048 * 2048) / 4;
  double s = 0.0;
  for (int i = blockIdx.x * 256 + threadIdx.x; i < n4; i += gridDim.x * 256) {
    float4 x = *(const float4*)(w + (size_t)i * 4);
    s += (double)fabsf(x.x) + (double)fabsf(x.y) + (double)fabsf(x.z) + (double)fabsf(x.w);
  }
  red[threadIdx.x] = s;
  __syncthreads();
  for (int o = 128; o > 0; o >>= 1) {
    if ((int)threadIdx.x < o) red[threadIdx.x] += red[threadIdx.x + o];
    __syncthreads();
  }
  if (threadIdx.x == 0) atomicAdd(out + seg, red[0]);
}

// Fused ternary quant of Wq/Wk/Wv/Wqn (4 elems/thread; segment bounds are /4).
__global__ void k_wquant4(const float* __restrict__ Wq, const float* __restrict__ Wk,
                          const float* __restrict__ Wv, const float* __restrict__ Wqn,
                          unsigned short* __restrict__ wall, const double* __restrict__ sums) {
  size_t i = ((size_t)blockIdx.x * 256 + threadIdx.x) * 4;   // 0 .. 10485756
  const float* src; size_t off; double s; float inv;
  if (i < 4194304)      { src = Wq;  off = 0;       s = sums[0]; inv = INV_BIG; }
  else if (i < 5242880) { src = Wk;  off = 4194304; s = sums[1]; inv = INV_SMALL; }
  else if (i < 6291456) { src = Wv;  off = 5242880; s = sums[2]; inv = INV_SMALL; }
  else                  { src = Wqn; off = 6291456; s = sums[4]; inv = INV_BIG; }
  float ws = 1.0f / fmaxf((float)s * inv, 1e-5f);
  float4 x = *(const float4*)(src + (i - off));
  ushort4 o;
  o.x = tern(x.x, ws); o.y = tern(x.y, ws); o.z = tern(x.z, ws); o.w = tern(x.w, ws);
  *(ushort4*)(wall + i) = o;
}

// Single-weight ternary quant (Wo), 4 elems/thread.
__global__ void k_wquant(const float* __restrict__ w, unsigned short* __restrict__ wq,
                         const double* __restrict__ sum, float inv_n) {
  size_t i = ((size_t)blockIdx.x * 256 + threadIdx.x) * 4;
  float ws = 1.0f / fmaxf((float)(*sum) * inv_n, 1e-5f);
  float4 x = *(const float4*)(w + i);
  ushort4 o;
  o.x = tern(x.x, ws); o.y = tern(x.y, ws); o.z = tern(x.z, ws); o.w = tern(x.w, ws);
  *(ushort4*)(wq + i) = o;
}

// Per-token int8 absmax activation quant -> bf16 integer values (float4 path).
__global__ void k_aquant(const float* __restrict__ x, unsigned short* __restrict__ xq,
                         float* __restrict__ dq, int K) {
  int t = blockIdx.x;
  const float4* xr = (const float4*)(x + (size_t)t * K);
  const int K4 = K / 4;
  __shared__ float red[256];
  float m = 0.0f;
  for (int i = threadIdx.x; i < K4; i += 256) {
    float4 v = xr[i];
    m = fmaxf(m, fmaxf(fmaxf(fabsf(v.x), fabsf(v.y)), fmaxf(fabsf(v.z), fabsf(v.w))));
  }
  red[threadIdx.x] = m;
  __syncthreads();
  for (int o = 128; o > 0; o >>= 1) {
    if ((int)threadIdx.x < o) red[threadIdx.x] = fmaxf(red[threadIdx.x], red[threadIdx.x + o]);
    __syncthreads();
  }
  float amax = fmaxf(red[0], 1e-5f);
  float as = 127.0f / amax;
  ushort4* xo = (ushort4*)(xq + (size_t)t * K);
  for (int i = threadIdx.x; i < K4; i += 256) {
    float4 v = xr[i];
    ushort4 o;
    float q;
    q = fminf(fmaxf(rintf(v.x * as), -128.0f), 127.0f); o.x = (unsigned short)(__float_as_uint(q) >> 16);
    q = fminf(fmaxf(rintf(v.y * as), -128.0f), 127.0f); o.y = (unsigned short)(__float_as_uint(q) >> 16);
    q = fminf(fmaxf(rintf(v.z * as), -128.0f), 127.0f); o.z = (unsigned short)(__float_as_uint(q) >> 16);
    q = fminf(fmaxf(rintf(v.w * as), -128.0f), 127.0f); o.w = (unsigned short)(__float_as_uint(q) >> 16);
    xo[i] = o;
  }
  if (threadIdx.x == 0) dq[t] = amax / 127.0f;
}

// ---------------------------------------------------------------------------
// bf16-MFMA BitLinear GEMM, 128x128 tiles (R4 config — B-traffic-optimal for
// M=1024; R6 proved 64-tile doubling of B reads costs more than the occupancy
// gain). RoPE fused into the epilogue: pair (d,d+32) = (h,h+2) lives in the
// same thread; Q (bx<16) rotated fp32, K (bx 16..19) rotated + packed-bsplit.
__global__ __launch_bounds__(256) void k_gemm_mfma(
    const unsigned short* __restrict__ Aq, const unsigned short* __restrict__ Ball,
    const float* __restrict__ adq, const double* __restrict__ sums,
    const float2* __restrict__ ropetab,
    float* __restrict__ oQ, float* __restrict__ oK,
    float* __restrict__ oV, float* __restrict__ oQN, int mode) {
  __shared__ unsigned short As[128 * 72];
  __shared__ unsigned short Bs[128 * 72];
  const int t = threadIdx.x;
  const int lane = t & 63;
  const int row16 = lane & 15, q = lane >> 4;
  const int w = t >> 6;
  const int wm = (w >> 1) * 64, wn = (w & 1) * 64;
  const int bx = blockIdx.x;
  const int m0 = blockIdx.y * 128;
  const unsigned short* Bp = Ball + (size_t)bx * 128 * 2048;

  floatx4 acc[4][4];
#pragma unroll
  for (int g = 0; g < 4; ++g)
#pragma unroll
    for (int h = 0; h < 4; ++h) acc[g][h] = (floatx4){0.f, 0.f, 0.f, 0.f};

  for (int k0 = 0; k0 < 2048; k0 += 64) {
#pragma unroll
    for (int i = 0; i < 4; ++i) {
      int c = t + 256 * i;
      int row = c >> 3, g8 = c & 7;
      *(uint4*)&As[row * 72 + g8 * 8] =
          *(const uint4*)(Aq + (size_t)(m0 + row) * 2048 + k0 + g8 * 8);
      *(uint4*)&Bs[row * 72 + g8 * 8] =
          *(const uint4*)(Bp + (size_t)row * 2048 + k0 + g8 * 8);
    }
    __syncthreads();
#pragma unroll
    for (int kk = 0; kk < 2; ++kk) {
      short8 af[4], bf[4];
#pragma unroll
      for (int g = 0; g < 4; ++g)
        af[g] = *(const short8*)&As[(wm + g * 16 + row16) * 72 + kk * 32 + q * 8];
#pragma unroll
      for (int h = 0; h < 4; ++h)
        bf[h] = *(const short8*)&Bs[(wn + h * 16 + row16) * 72 + kk * 32 + q * 8];
#pragma unroll
      for (int g = 0; g < 4; ++g)
#pragma unroll
        for (int h = 0; h < 4; ++h)
          acc[g][h] = __builtin_amdgcn_mfma_f32_16x16x32_bf16(af[g], bf[h], acc[g][h], 0, 0, 0);
    }
    __syncthreads();
  }

  float* outp; int Nout, nb0; float wdq;
  if (mode == 1)      { outp = oQ;  Nout = 2048; nb0 = bx * 128;        wdq = fmaxf((float)sums[3] * INV_BIG,   1e-5f); }
  else if (bx < 16)   { outp = oQ;  Nout = 2048; nb0 = bx * 128;        wdq = fmaxf((float)sums[0] * INV_BIG,   1e-5f); }
  else if (bx < 20)   { outp = oK;  Nout = 512;  nb0 = (bx - 16) * 128; wdq = fmaxf((float)sums[1] * INV_SMALL, 1e-5f); }
  else if (bx < 24)   { outp = oV;  Nout = 512;  nb0 = (bx - 20) * 128; wdq = fmaxf((float)sums[2] * INV_SMALL, 1e-5f); }
  else                { outp = oQN; Nout = 2048; nb0 = (bx - 24) * 128; wdq = fmaxf((float)sums[4] * INV_BIG,   1e-5f); }

  if (mode == 0 && bx < 20) {
    // RoPE epilogue. head-relative d = (wn + h*16 + row16) & 63 = h*16 + row16.
#pragma unroll
    for (int g = 0; g < 4; ++g)
#pragma unroll
      for (int r = 0; r < 4; ++r) {
        int m = m0 + wm + g * 16 + q * 4 + r;
        float s = adq[m] * wdq;
        float2 cs0 = ropetab[m * 32 + row16];        // d = row16
        float2 cs1 = ropetab[m * 32 + 16 + row16];   // d = 16 + row16
        float v0 = acc[g][0][r] * s, v1 = acc[g][1][r] * s;
        float v2 = acc[g][2][r] * s, v3 = acc[g][3][r] * s;
        float o0 = v0 * cs0.x - v2 * cs0.y;
        float o2 = v2 * cs0.x + v0 * cs0.y;
        float o1 = v1 * cs1.x - v3 * cs1.y;
        float o3 = v3 * cs1.x + v1 * cs1.y;
        size_t base = (size_t)m * Nout + nb0 + wn;
        if (bx < 16) {   // Q: fp32
          outp[base + row16]      = o0;
          outp[base + 16 + row16] = o1;
          outp[base + 32 + row16] = o2;
          outp[base + 48 + row16] = o3;
        } else {         // K: packed hi|lo<<16
          unsigned int* ko = (unsigned int*)outp;
          unsigned short hi, lo;
          bsplit(o0, hi, lo); ko[base + row16]      = (unsigned int)hi | ((unsigned int)lo << 16);
          bsplit(o1, hi, lo); ko[base + 16 + row16] = (unsigned int)hi | ((unsigned int)lo << 16);
          bsplit(o2, hi, lo); ko[base + 32 + row16] = (unsigned int)hi | ((unsigned int)lo << 16);
          bsplit(o3, hi, lo); ko[base + 48 + row16] = (unsigned int)hi | ((unsigned int)lo << 16);
        }
      }
  } else {
#pragma unroll
    for (int g = 0; g < 4; ++g)
#pragma unroll
      for (int r = 0; r < 4; ++r) {
        int m = m0 + wm + g * 16 + q * 4 + r;
        float s = adq[m] * wdq;
#pragma unroll
        for (int h = 0; h < 4; ++h)
          outp[(size_t)m * Nout + nb0 + wn + h * 16 + row16] = acc[g][h][r] * s;
      }
  }
}

// ---------------------------------------------------------------------------
// Merged prep: blocks [0,1152) = V transpose+split; blocks >= 1152 = in-place
// packed hi/lo split of kbk (4 elems/thread; input restored each launch).
__global__ __launch_bounds__(256) void k_prep(
    const float* __restrict__ kbv, const float* __restrict__ Vb,
    unsigned int* __restrict__ vtKB, unsigned int* __restrict__ vtP,
    float* __restrict__ kbk) {
  __shared__ float Lf[64 * 65];
  const int b = blockIdx.x;
  if (b >= 1152) {
    int i = (b - 1152) * 1024 + threadIdx.x * 4;
    float4 x = *(const float4*)(kbk + i);
    unsigned short hi, lo;
    uint4 o;
    bsplit(x.x, hi, lo); o.x = (unsigned int)hi | ((unsigned int)lo << 16);
    bsplit(x.y, hi, lo); o.y = (unsigned int)hi | ((unsigned int)lo << 16);
    bsplit(x.z, hi, lo); o.z = (unsigned int)hi | ((unsigned int)lo << 16);
    bsplit(x.w, hi, lo); o.w = (unsigned int)hi | ((unsigned int)lo << 16);
    *(uint4*)((unsigned int*)kbk + i) = o;
    return;
  }
  const float* src; unsigned int* dst; int srcStride, dstStride;
  if (b < 1024) {
    int h = b >> 5, kt = b & 31;
    src = kbv + ((size_t)h * cKB + kt * 64) * 64;
    srcStride = 64;
    dst = vtKB + (size_t)(h * 64) * 2048 + kt * 64;
    dstStride = 2048;
  } else {
    int bb = b - 1024;
    int hkv = bb >> 4, kt = bb & 15;
    src = Vb + (size_t)(kt * 64) * 512 + hkv * 64;
    srcStride = 512;
    dst = vtP + (size_t)(hkv * 64) * 1024 + kt * 64;
    dstStride = 1024;
  }
  const int t = threadIdx.x;
#pragma unroll
  for (int i = 0; i < 4; ++i) {
    int c = t + 256 * i;
    int row = c >> 4, c4 = (c & 15) * 4;
    float4 x = *(const float4*)(src + (size_t)row * srcStride + c4);
    Lf[row * 65 + c4 + 0] = x.x;
    Lf[row * 65 + c4 + 1] = x.y;
    Lf[row * 65 + c4 + 2] = x.z;
    Lf[row * 65 + c4 + 3] = x.w;
  }
  __syncthreads();
  const int lane = t & 63, w = t >> 6;
#pragma unroll
  for (int it = 0; it < 16; ++it) {
    int d = w + 4 * it;
    float x = Lf[lane * 65 + d];
    unsigned short hi, lo;
    bsplit(x, hi, lo);
    dst[(size_t)d * dstStride + lane] = (unsigned int)hi | ((unsigned int)lo << 16);
  }
}

// ---------------------------------------------------------------------------
// Split-bf16 MFMA flash attention (R6 version, unchanged: q-tile 64, 512
// blocks = 2/CU, 3 blocks/CU LDS cap, __expf softmax).
__global__ __launch_bounds__(256, 3) void k_attn_mfma(
    const float* __restrict__ Qr, float* qnctx,
    const unsigned int* __restrict__ Kp,    // prompt K packed [1024][512]
    const unsigned int* __restrict__ kbkP,  // KB K packed [h][2048][64]
    const unsigned int* __restrict__ vtKB,  // KB V^T packed [h*64+d][2048]
    const unsigned int* __restrict__ vtP) { // prompt V^T packed [hkv*64+d][1024]
  __shared__ unsigned short Khi[64 * 72], Klo[64 * 72];
  __shared__ unsigned short Vhi[64 * 72], Vlo[64 * 72];   // [d][key]
  __shared__ unsigned int   Pbuf[4][16 * 68];             // per-wave

  const int t = threadIdx.x;
  const int lane = t & 63;
  const int col = lane & 15;
  const int quad = lane >> 4;
  const int w = t >> 6;
  const int h = blockIdx.x;
  const int q0 = blockIdx.y * 64;
  const int hkv = h >> 2;
  const float kbbias = 0.69314718055994531f;   // log(4096)-log(2048)
  unsigned int* Pw = &Pbuf[w][0];

  short8 qh[2], ql[2];
  auto load_q = [&](const float* base) {
#pragma unroll
    for (int kk = 0; kk < 2; ++kk) {
      const float* p = base + (size_t)(q0 + w * 16 + col) * 2048 + h * 64 + kk * 32 + quad * 8;
      float4 a = *(const float4*)p;
      float4 b = *(const float4*)(p + 4);
      float xs[8] = {a.x, a.y, a.z, a.w, b.x, b.y, b.z, b.w};
#pragma unroll
      for (int j = 0; j < 8; ++j) {
        unsigned short hi, lo;
        bsplit(xs[j] * 0.125f, hi, lo);   // fold 1/sqrt(64), exact
        qh[kk][j] = (short)hi;
        ql[kk][j] = (short)lo;
      }
    }
  };
  load_q(qnctx);   // kb_q first (not rotated)

  floatx4 acco[4];
  float m_[4], l_[4];
#pragma unroll
  for (int nt = 0; nt < 4; ++nt) acco[nt] = (floatx4){0.f, 0.f, 0.f, 0.f};
#pragma unroll
  for (int r = 0; r < 4; ++r) { m_[r] = -3.0e38f; l_[r] = 0.f; }

  const int ntiles = 32 + (q0 >> 6) + 1;
  for (int kt = 0; kt < ntiles; ++kt) {
    const bool isKB = kt < 32;
    const int k0 = isKB ? kt * 64 : (kt - 32) * 64;
    if (kt == 32) load_q(Qr);   // switch to rotated prompt q

    {
      const unsigned int* ksrc = isKB ? kbkP + ((size_t)h * cKB + k0) * 64
                                      : Kp + (size_t)k0 * 512 + hkv * 64;
      const int kstride = isKB ? 64 : 512;
      const unsigned int* vsrc = isKB ? vtKB + (size_t)(h * 64) * 2048 + k0
                                      : vtP + (size_t)(hkv * 64) * 1024 + k0;
      const int vstride = isKB ? 2048 : 1024;
#pragma unroll
      for (int i = 0; i < 4; ++i) {
        int c = t + 256 * i;
        int row = c >> 4, c4 = (c & 15) * 4;
        uint4 v = *(const uint4*)(ksrc + (size_t)row * kstride + c4);
        *(uint2*)&Khi[row * 72 + c4] =
            make_uint2((v.x & 0xffffu) | (v.y << 16), (v.z & 0xffffu) | (v.w << 16));
        *(uint2*)&Klo[row * 72 + c4] =
            make_uint2((v.x >> 16) | (v.y & 0xffff0000u), (v.z >> 16) | (v.w & 0xffff0000u));
        uint4 u = *(const uint4*)(vsrc + (size_t)row * vstride + c4);
        *(uint2*)&Vhi[row * 72 + c4] =
            make_uint2((u.x & 0xffffu) | (u.y << 16), (u.z & 0xffffu) | (u.w << 16));
        *(uint2*)&Vlo[row * 72 + c4] =
            make_uint2((u.x >> 16) | (u.y & 0xffff0000u), (u.z >> 16) | (u.w & 0xffff0000u));
      }
    }
    __syncthreads();

    floatx4 accs[4];
#pragma unroll
    for (int nt = 0; nt < 4; ++nt) accs[nt] = (floatx4){0.f, 0.f, 0.f, 0.f};
#pragma unroll
    for (int kk = 0; kk < 2; ++kk) {
#pragma unroll
      for (int nt = 0; nt < 4; ++nt) {
        const int ko = (nt * 16 + col) * 72 + kk * 32 + quad * 8;
        short8 khh = *(const short8*)&Khi[ko];
        short8 kll = *(const short8*)&Klo[ko];
        accs[nt] = __builtin_amdgcn_mfma_f32_16x16x32_bf16(qh[kk], khh, accs[nt], 0, 0, 0);
        accs[nt] = __builtin_amdgcn_mfma_f32_16x16x32_bf16(ql[kk], khh, accs[nt], 0, 0, 0);
        accs[nt] = __builtin_amdgcn_mfma_f32_16x16x32_bf16(qh[kk], kll, accs[nt], 0, 0, 0);
      }
    }

    float sv[4][4];
#pragma unroll
    for (int nt = 0; nt < 4; ++nt) {
      int kg = k0 + nt * 16 + col;
#pragma unroll
      for (int r = 0; r < 4; ++r) {
        int qg = q0 + w * 16 + quad * 4 + r;
        float b = isKB ? kbbias : ((kg <= qg) ? 0.0f : -1e9f);
        sv[nt][r] = accs[nt][r] + b;
      }
    }
#pragma unroll
    for (int r = 0; r < 4; ++r) {
      float rmax = fmaxf(fmaxf(sv[0][r], sv[1][r]), fmaxf(sv[2][r], sv[3][r]));
#pragma unroll
      for (int off = 8; off; off >>= 1) rmax = fmaxf(rmax, __shfl_xor(rmax, off));
      float mnew = fmaxf(m_[r], rmax);
      float alpha = __expf(m_[r] - mnew);
      float psum = 0.f;
#pragma unroll
      for (int nt = 0; nt < 4; ++nt) {
        float p = __expf(sv[nt][r] - mnew);
        sv[nt][r] = p;
        psum += p;
      }
#pragma unroll
      for (int off = 8; off; off >>= 1) psum += __shfl_xor(psum, off);
      l_[r] = l_[r] * alpha + psum;
      m_[r] = mnew;
#pragma unroll
      for (int nt = 0; nt < 4; ++nt) acco[nt][r] *= alpha;
    }

#pragma unroll
    for (int nt = 0; nt < 4; ++nt)
#pragma unroll
      for (int r = 0; r < 4; ++r) {
        unsigned short ph, pl;
        bsplit(sv[nt][r], ph, pl);
        Pw[(quad * 4 + r) * 68 + nt * 16 + col] = (unsigned int)ph | ((unsigned int)pl << 16);
      }

#pragma unroll
    for (int kk = 0; kk < 2; ++kk) {
      uint4 pa = *(const uint4*)&Pw[col * 68 + kk * 32 + quad * 8];
      uint4 pb = *(const uint4*)&Pw[col * 68 + kk * 32 + quad * 8 + 4];
      union { unsigned int u[4]; short8 s; } uh, ul;
      uh.u[0] = (pa.x & 0xffffu) | (pa.y << 16);
      uh.u[1] = (pa.z & 0xffffu) | (pa.w << 16);
      uh.u[2] = (pb.x & 0xffffu) | (pb.y << 16);
      uh.u[3] = (pb.z & 0xffffu) | (pb.w << 16);
      ul.u[0] = (pa.x >> 16) | (pa.y & 0xffff0000u);
      ul.u[1] = (pa.z >> 16) | (pa.w & 0xffff0000u);
      ul.u[2] = (pb.x >> 16) | (pb.y & 0xffff0000u);
      ul.u[3] = (pb.z >> 16) | (pb.w & 0xffff0000u);
      short8 ph8 = uh.s, pl8 = ul.s;
#pragma unroll
      for (int nt = 0; nt < 4; ++nt) {
        const int vo = (nt * 16 + col) * 72 + kk * 32 + quad * 8;
        short8 vhh = *(const short8*)&Vhi[vo];
        short8 vll = *(const short8*)&Vlo[vo];
        acco[nt] = __builtin_amdgcn_mfma_f32_16x16x32_bf16(ph8, vhh, acco[nt], 0, 0, 0);
        acco[nt] = __builtin_amdgcn_mfma_f32_16x16x32_bf16(pl8, vhh, acco[nt], 0, 0, 0);
        acco[nt] = __builtin_amdgcn_mfma_f32_16x16x32_bf16(ph8, vll, acco[nt], 0, 0, 0);
      }
    }
    __syncthreads();   // all K/V reads done before next staging overwrite
  }

#pragma unroll
  for (int r = 0; r < 4; ++r) {
    float linv = 1.0f / l_[r];
#pragma unroll
    for (int nt = 0; nt < 4; ++nt)
      qnctx[(size_t)(q0 + w * 16 + quad * 4 + r) * 2048 + h * 64 + nt * 16 + col] =
          acco[nt][r] * linv;
  }
}

// ---------------------------------------------------------------------------
extern "C" void kernel_launch(void* const* d_in, const int* in_sizes, int n_in,
                              void* d_out, int out_size, void* d_ws, size_t ws_size,
                              hipStream_t stream) {
  (void)in_sizes; (void)n_in; (void)out_size; (void)ws_size;
  const float* hidden = (const float*)d_in[0];
  float* kbk = (float*)d_in[2];              // packed-split in place (restored each launch)
  const float* kbv = (const float*)d_in[3];
  const float* Wq  = (const float*)d_in[4];
  const float* Wk  = (const float*)d_in[5];
  const float* Wv  = (const float*)d_in[6];
  const float* Wo  = (const float*)d_in[7];
  const float* Wqn = (const float*)d_in[8];
  const int*   pos = (const int*)d_in[9];

  char* ws = (char*)d_ws;
  double* sums = (double*)(ws + WS_SUMS);
  float* dq1 = (float*)(ws + WS_DQ1);
  float* dq2 = (float*)(ws + WS_DQ2);
  unsigned short* xq   = (unsigned short*)(ws + WS_XQ);
  unsigned short* wall = (unsigned short*)(ws + WS_WALL);
  unsigned int* vtKB = (unsigned int*)(ws + WS_WALL);              // after GEMM
  unsigned int* vtP  = (unsigned int*)(ws + WS_WALL + 16777216);   // after GEMM
  unsigned short* wqo  = (unsigned short*)(ws + WS_QB);            // after attn
  float* Qb  = (float*)(ws + WS_QB);
  float* Kb  = (float*)(ws + WS_KB);
  float* Vb  = (float*)(ws + WS_VB);
  float* QNC = (float*)(ws + WS_QN);   // kb_q, then CTX
  float2* ropetab = (float2*)(ws + WS_ROPET);

  hipMemsetAsync(sums, 0, 64, stream);

  k_ropetab<<<128, 256, 0, stream>>>(pos, ropetab);
  k_abssum5<<<dim3(128, 5), 256, 0, stream>>>(Wq, Wk, Wv, Wo, Wqn, sums);
  k_wquant4<<<10240, 256, 0, stream>>>(Wq, Wk, Wv, Wqn, wall, sums);
  k_aquant<<<cQ, 256, 0, stream>>>(hidden, xq, dq1, cH);

  // Fused Q/K/V/QN GEMM with RoPE epilogue: 128x128 tiles, grid 40x8
  k_gemm_mfma<<<dim3(40, 8), 256, 0, stream>>>(xq, wall, dq1, sums, ropetab,
                                               Qb, Kb, Vb, QNC, 0);

  // V transpose+split (1152 blocks) + kbk packed split (4096 blocks)
  k_prep<<<1152 + 4096, 256, 0, stream>>>(kbv, Vb, vtKB, vtP, kbk);

  k_attn_mfma<<<dim3(cNH, cQ / 64), 256, 0, stream>>>(
      Qb, QNC, (const unsigned int*)Kb, (const unsigned int*)kbk, vtKB, vtP);

  k_wquant<<<4096, 256, 0, stream>>>(Wo, wqo, sums + 3, INV_BIG);
  k_aquant<<<cQ, 256, 0, stream>>>(QNC, xq, dq2, cH);

  // O projection: 128x128 tiles, grid 16x8
  k_gemm_mfma<<<dim3(16, 8), 256, 0, stream>>>(xq, wqo, dq2, sums, ropetab,
                                               (float*)d_out, nullptr, nullptr, nullptr, 1);
}